// Round 2
// baseline (15263.078 us; speedup 1.0000x reference)
//
#include <hip/hip_runtime.h>
#include <cstdint>
#include <cstddef>

// Problem constants
#define HN 304      // hidden size
#define G3 912      // 3*HN gate rows
#define US 76       // hidden units per slice (HN/4)
#define RS 228      // rows per slice (3*US)
#define NB 64       // batch
#define TSTEPS 1024 // encoder steps
#define LDEC 127    // decoder steps actually needed (L-1)
#define DCLS 128    // vocab / classes

// Output layout (floats): [softmax_cal 8128*128][target_cal 8128][asr_outputs 8128]
#define OUT_O1 1040384
#define OUT_O2 1048512

// Workspace layout (bytes). Proven available in R1: ws_size >= 239,702,784.
static const size_t OFF_GI   = 0;             // 64*1024*912 f32 = 239,075,328 B
static const size_t OFF_HG   = 239075328ull;  // hglob: 2*64*304 f32 = 155,648 B
static const size_t OFF_SYNC = 239230976ull;  // 64 batches * 16 ints (64B line each) = 4,096 B
static const size_t OFF_ABRT = 239235072ull;  // 256 B
static const size_t OFF_TAB  = 239235328ull;  // 128*912 f32 = 466,944 B
static const size_t WS_NEED  = 239702272ull;  // <= 239,702,784 proven bound

// sync line per batch b: ints [0..3]=flag[s], [4..7]=argmax val bits[s], [8..11]=argmax idx[s]

// ---------------------------------------------------------------------------
// Phase 1: gi[b,t,:] = x[b,t,:] @ enc_Wih^T + enc_bih   (M=65536, N=912, K=304)
// ---------------------------------------------------------------------------
__global__ __launch_bounds__(256) void gi_gemm(const float* __restrict__ X,
                                               const float* __restrict__ W,
                                               const float* __restrict__ bias,
                                               float* __restrict__ out)
{
    __shared__ float xs[16][68];
    __shared__ float wsm[16][68];
    const int tid = threadIdx.x;
    const int m0 = blockIdx.x * 64;
    const int n0 = blockIdx.y * 64;
    const int tx = tid & 15, ty = tid >> 4;
    const int lr = tid >> 2;
    const int lk = (tid & 3) * 4;
    float c[4][4];
#pragma unroll
    for (int i = 0; i < 4; ++i)
#pragma unroll
        for (int j = 0; j < 4; ++j) c[i][j] = 0.f;

    for (int k0 = 0; k0 < HN; k0 += 16) {
        float4 xv = *(const float4*)(X + (size_t)(m0 + lr) * HN + k0 + lk);
        float4 wv = make_float4(0.f, 0.f, 0.f, 0.f);
        if (n0 + lr < G3) wv = *(const float4*)(W + (size_t)(n0 + lr) * HN + k0 + lk);
        xs[lk + 0][lr] = xv.x; xs[lk + 1][lr] = xv.y; xs[lk + 2][lr] = xv.z; xs[lk + 3][lr] = xv.w;
        wsm[lk + 0][lr] = wv.x; wsm[lk + 1][lr] = wv.y; wsm[lk + 2][lr] = wv.z; wsm[lk + 3][lr] = wv.w;
        __syncthreads();
#pragma unroll
        for (int kk = 0; kk < 16; ++kk) {
            const float4 a4 = *(const float4*)&xs[kk][ty * 4];
            const float4 b4 = *(const float4*)&wsm[kk][tx * 4];
            c[0][0] += a4.x * b4.x; c[0][1] += a4.x * b4.y; c[0][2] += a4.x * b4.z; c[0][3] += a4.x * b4.w;
            c[1][0] += a4.y * b4.x; c[1][1] += a4.y * b4.y; c[1][2] += a4.y * b4.z; c[1][3] += a4.y * b4.w;
            c[2][0] += a4.z * b4.x; c[2][1] += a4.z * b4.y; c[2][2] += a4.z * b4.z; c[2][3] += a4.z * b4.w;
            c[3][0] += a4.w * b4.x; c[3][1] += a4.w * b4.y; c[3][2] += a4.w * b4.z; c[3][3] += a4.w * b4.w;
        }
        __syncthreads();
    }
#pragma unroll
    for (int i = 0; i < 4; ++i) {
        const int m = m0 + ty * 4 + i;
#pragma unroll
        for (int j = 0; j < 4; ++j) {
            const int n = n0 + tx * 4 + j;
            if (n < G3) out[(size_t)m * G3 + n] = c[i][j] + bias[n];
        }
    }
}

// ---------------------------------------------------------------------------
// Phase 1b: decoder input-projection table
// ---------------------------------------------------------------------------
__global__ __launch_bounds__(256) void table_k(const float* __restrict__ emb,
                                               const float* __restrict__ Wih,
                                               const float* __restrict__ bih,
                                               float* __restrict__ tab)
{
    const int idx = blockIdx.x * 256 + threadIdx.x;  // 456*256 = 116736 = 128*912
    const int d = idx / G3;
    const int R = idx - d * G3;
    const float4* e4 = (const float4*)(emb + (size_t)d * HN);
    const float4* w4 = (const float4*)(Wih + (size_t)R * HN);
    float acc = 0.f;
#pragma unroll
    for (int j = 0; j < 76; ++j) {
        const float4 e = e4[j], w = w4[j];
        acc += e.x * w.x; acc += e.y * w.y; acc += e.z * w.z; acc += e.w * w.w;
    }
    tab[idx] = acc + bih[R];
}

// target_cal output
__global__ void tcal_k(const int* __restrict__ target, float* __restrict__ out)
{
    const int i = blockIdx.x * 256 + threadIdx.x;
    if (i < NB * LDEC) {
        const int b = i / LDEC;
        const int t = i - b * LDEC;
        out[OUT_O1 + i] = (float)target[b * 128 + t + 1];
    }
}

// relaxed spin until *f >= tgt, then one acquire load (sync edge) — avoids
// per-poll L1-invalidate traffic that acquire-in-loop would generate.
__device__ __forceinline__ void spin_ge(int* f, int tgt, int* abortf)
{
    int g = 0;
    while (__hip_atomic_load(f, __ATOMIC_RELAXED, __HIP_MEMORY_SCOPE_AGENT) < tgt) {
        if ((++g & 255) == 0) {
            if (__hip_atomic_load(abortf, __ATOMIC_RELAXED, __HIP_MEMORY_SCOPE_AGENT) != 0) return;
            if (g > (1 << 22)) {  // deadlock valve: fail loudly, don't hang the graph
                __hip_atomic_store(abortf, 1, __ATOMIC_RELAXED, __HIP_MEMORY_SCOPE_AGENT);
                return;
            }
        }
    }
    (void)__hip_atomic_load(f, __ATOMIC_ACQUIRE, __HIP_MEMORY_SCOPE_AGENT);
}

// ---------------------------------------------------------------------------
// Phase 2: persistent recurrence. 256 WGs x 1024 threads, 1 WG/CU.
// WG w: batch b = w & 63, slice s = w >> 6. Partners are 64 apart in blockIdx
// (same XCD under round-robin dispatch — locality heuristic only).
// Sync: per-(b,s) monotonic flag in a per-batch 64B line; release-store by
// producer tid0 after __syncthreads drains the h stores; consumers spin+load.
// Flag schedule: encoder step t publishes h with flag t+1 (1..1024);
// decoder step t: h flag = 1025+2t, argmax flag = 1026+2t. Monotone.
// ---------------------------------------------------------------------------
__global__ __launch_bounds__(1024) void rnn_persist(
    const float* __restrict__ gi,
    const float* __restrict__ encWhh, const float* __restrict__ encBhh,
    const float* __restrict__ decWhh, const float* __restrict__ decBhh,
    const float* __restrict__ tab,
    const float* __restrict__ linW, const float* __restrict__ linB,
    const int* __restrict__ target,
    float* hglob, int* syncA, int* abortf, float* out)
{
    const int w = blockIdx.x;
    const int b = w & 63;
    const int s = w >> 6;
    const int tid = threadIdx.x;

    __shared__ alignas(16) float hbuf[HN];
    __shared__ alignas(16) float part[4][RS];
    __shared__ alignas(16) float lpart[32][9];
    __shared__ float logit_s[32];
    __shared__ int tok_s;

    const int ks = tid / RS;           // k-slice 0..3 (tid>=912 idle in GEMV)
    const int lr = tid - ks * RS;      // local row 0..227
    const bool comp = (tid < 912);
    const int g = lr / US;             // gate 0=r,1=z,2=n
    const int ul = lr - g * US;        // unit within slice
    const int Rrow = g * HN + s * US + ul;
    const int u = s * US + tid;        // global hidden unit for tid<76
    const int cq = tid / US;           // slice owning unit `tid` (tid<304)

    int* syncl = syncA + b * 16;       // this batch's 64B sync line

    // ---- encoder Whh slice into registers (76 f32 per thread)
    float4 wreg[19];
    if (comp) {
        const float4* wp = (const float4*)(encWhh + (size_t)Rrow * HN + (size_t)ks * US);
#pragma unroll
        for (int j = 0; j < 19; ++j) wreg[j] = wp[j];
    }
    float b_r = 0.f, b_z = 0.f, b_n = 0.f;
    if (tid < US) { b_r = encBhh[u]; b_z = encBhh[HN + u]; b_n = encBhh[2 * HN + u]; }

    for (int i = tid; i < HN; i += 1024) hbuf[i] = 0.f;   // h0 = 0
    __syncthreads();

    const float* gib = gi + (size_t)b * TSTEPS * G3;

    // ================= encoder: 1024 steps =================
    for (int t = 0; t < TSTEPS; ++t) {
        const int flagv = t + 1;
        const int buf = flagv & 1;
        float gr = 0.f, gz = 0.f, gn = 0.f;
        if (tid < US) {                       // gi prefetch, hidden behind GEMV
            const float* gp = gib + (size_t)t * G3;
            gr = gp[u]; gz = gp[HN + u]; gn = gp[2 * HN + u];
        }
        if (comp) {
            const float4* hp = (const float4*)(hbuf + ks * US);
            float acc = 0.f;
#pragma unroll
            for (int j = 0; j < 19; ++j) {
                const float4 h4 = hp[j], w4 = wreg[j];
                acc += w4.x * h4.x; acc += w4.y * h4.y; acc += w4.z * h4.z; acc += w4.w * h4.w;
            }
            part[ks][lr] = acc;               // conflict-free: consecutive lr -> consecutive banks
        }
        __syncthreads();
        if (tid < US) {
            const float ghr = part[0][tid] + part[1][tid] + part[2][tid] + part[3][tid] + b_r;
            const float ghz = part[0][US + tid] + part[1][US + tid] + part[2][US + tid] + part[3][US + tid] + b_z;
            const float ghn = part[0][2 * US + tid] + part[1][2 * US + tid] + part[2][2 * US + tid] + part[3][2 * US + tid] + b_n;
            const float r = 1.f / (1.f + expf(-(gr + ghr)));
            const float z = 1.f / (1.f + expf(-(gz + ghz)));
            const float n = tanhf(gn + r * ghn);
            const float hnew = (1.f - z) * n + z * hbuf[u];
            hbuf[u] = hnew;                   // own slice direct to LDS
            __hip_atomic_store(&hglob[buf * NB * HN + b * HN + u], hnew,
                               __ATOMIC_RELAXED, __HIP_MEMORY_SCOPE_AGENT);
        }
        __syncthreads();                      // drains all waves' global stores
        if (tid == 0)
            __hip_atomic_store(&syncl[s], flagv, __ATOMIC_RELEASE, __HIP_MEMORY_SCOPE_AGENT);
        if (tid < HN && cq != s) {            // fetch remote slices
            spin_ge(&syncl[cq], flagv, abortf);
            hbuf[tid] = __hip_atomic_load(&hglob[buf * NB * HN + b * HN + tid],
                                          __ATOMIC_RELAXED, __HIP_MEMORY_SCOPE_AGENT);
        }
        __syncthreads();
    }

    // ================= decoder: 127 steps =================
    if (comp) {
        const float4* wp = (const float4*)(decWhh + (size_t)Rrow * HN + (size_t)ks * US);
#pragma unroll
        for (int j = 0; j < 19; ++j) wreg[j] = wp[j];
    }
    if (tid < US) { b_r = decBhh[u]; b_z = decBhh[HN + u]; b_n = decBhh[2 * HN + u]; }

    int tok = target[b * 128];         // target[b,0,0]
    const int lrow = tid >> 3;         // logit row within slice (tid<256)
    const int lks = tid & 7;           // 8 k-slices of 38

    for (int t = 0; t < LDEC; ++t) {
        const int hflagv = 1025 + 2 * t;
        const int aflagv = 1026 + 2 * t;
        const int buf = hflagv & 1;
        float gr = 0.f, gz = 0.f, gn = 0.f;
        if (tid < US) {
            const float* tp = tab + (size_t)tok * G3;
            gr = tp[u]; gz = tp[HN + u]; gn = tp[2 * HN + u];
        }
        if (comp) {
            const float4* hp = (const float4*)(hbuf + ks * US);
            float acc = 0.f;
#pragma unroll
            for (int j = 0; j < 19; ++j) {
                const float4 h4 = hp[j], w4 = wreg[j];
                acc += w4.x * h4.x; acc += w4.y * h4.y; acc += w4.z * h4.z; acc += w4.w * h4.w;
            }
            part[ks][lr] = acc;
        }
        __syncthreads();
        if (tid < US) {
            const float ghr = part[0][tid] + part[1][tid] + part[2][tid] + part[3][tid] + b_r;
            const float ghz = part[0][US + tid] + part[1][US + tid] + part[2][US + tid] + part[3][US + tid] + b_z;
            const float ghn = part[0][2 * US + tid] + part[1][2 * US + tid] + part[2][2 * US + tid] + part[3][2 * US + tid] + b_n;
            const float r = 1.f / (1.f + expf(-(gr + ghr)));
            const float z = 1.f / (1.f + expf(-(gz + ghz)));
            const float n = tanhf(gn + r * ghn);
            const float hnew = (1.f - z) * n + z * hbuf[u];
            hbuf[u] = hnew;
            __hip_atomic_store(&hglob[buf * NB * HN + b * HN + u], hnew,
                               __ATOMIC_RELAXED, __HIP_MEMORY_SCOPE_AGENT);
        }
        __syncthreads();
        if (tid == 0)
            __hip_atomic_store(&syncl[s], hflagv, __ATOMIC_RELEASE, __HIP_MEMORY_SCOPE_AGENT);
        if (tid < HN && cq != s) {
            spin_ge(&syncl[cq], hflagv, abortf);
            hbuf[tid] = __hip_atomic_load(&hglob[buf * NB * HN + b * HN + tid],
                                          __ATOMIC_RELAXED, __HIP_MEMORY_SCOPE_AGENT);
        }
        __syncthreads();                      // hbuf fresh for logits

        // logits rows [32s, 32s+32)
        if (tid < 256) {
            const float2* wl = (const float2*)(linW + (size_t)(s * 32 + lrow) * HN + (size_t)lks * 38);
            const float2* hl = (const float2*)(hbuf + lks * 38);
            float a = 0.f;
#pragma unroll
            for (int j = 0; j < 19; ++j) { const float2 wv = wl[j], hv = hl[j]; a += wv.x * hv.x; a += wv.y * hv.y; }
            lpart[lrow][lks] = a;
        }
        __syncthreads();
        if (tid < 32) {
            const float lg = lpart[tid][0] + lpart[tid][1] + lpart[tid][2] + lpart[tid][3]
                           + lpart[tid][4] + lpart[tid][5] + lpart[tid][6] + lpart[tid][7]
                           + linB[s * 32 + tid];
            logit_s[tid] = lg;
            out[((size_t)b * LDEC + t) * DCLS + s * 32 + tid] = lg;   // softmax_cal
        }
        __syncthreads();
        if (tid == 0) {
            float bv = logit_s[0]; int bi = 0;
            for (int i = 1; i < 32; ++i) { const float v = logit_s[i]; if (v > bv) { bv = v; bi = i; } }
            __hip_atomic_store((float*)&syncl[4 + s], bv, __ATOMIC_RELAXED, __HIP_MEMORY_SCOPE_AGENT);
            __hip_atomic_store(&syncl[8 + s], s * 32 + bi, __ATOMIC_RELAXED, __HIP_MEMORY_SCOPE_AGENT);
            __hip_atomic_store(&syncl[s], aflagv, __ATOMIC_RELEASE, __HIP_MEMORY_SCOPE_AGENT);
            float gbv = 0.f; int gbi = 0;
            for (int q = 0; q < 4; ++q) {   // ascending q + strict '>' == first-max tie-break
                spin_ge(&syncl[q], aflagv, abortf);
                const float v = __hip_atomic_load((float*)&syncl[4 + q], __ATOMIC_RELAXED, __HIP_MEMORY_SCOPE_AGENT);
                const int ii = __hip_atomic_load(&syncl[8 + q], __ATOMIC_RELAXED, __HIP_MEMORY_SCOPE_AGENT);
                if (q == 0 || v > gbv) { gbv = v; gbi = ii; }
            }
            tok_s = gbi;
            if (s == 0) out[OUT_O2 + (size_t)b * LDEC + t] = (float)gbi;  // asr_outputs
        }
        __syncthreads();
        tok = tok_s;
    }
}

// ---------------------------------------------------------------------------
extern "C" void kernel_launch(void* const* d_in, const int* in_sizes, int n_in,
                              void* d_out, int out_size, void* d_ws, size_t ws_size,
                              hipStream_t stream)
{
    (void)in_sizes; (void)n_in; (void)out_size;
    const float* x      = (const float*)d_in[0];
    const int*   target = (const int*)  d_in[1];
    const float* emb    = (const float*)d_in[2];
    const float* encWih = (const float*)d_in[3];
    const float* encWhh = (const float*)d_in[4];
    const float* encBih = (const float*)d_in[5];
    const float* encBhh = (const float*)d_in[6];
    const float* decWih = (const float*)d_in[7];
    const float* decWhh = (const float*)d_in[8];
    const float* decBih = (const float*)d_in[9];
    const float* decBhh = (const float*)d_in[10];
    const float* linW   = (const float*)d_in[11];
    const float* linB   = (const float*)d_in[12];
    float* out = (float*)d_out;
    char* ws = (char*)d_ws;

    if (ws_size < WS_NEED) return;  // insufficient scratch: fail visibly

    float* gi    = (float*)(ws + OFF_GI);
    float* hglob = (float*)(ws + OFF_HG);
    int*   syncA = (int*)  (ws + OFF_SYNC);
    int*   abrt  = (int*)  (ws + OFF_ABRT);
    float* tab   = (float*)(ws + OFF_TAB);

    // only flags/abort need zeroing (hglob is written before first read)
    hipMemsetAsync(ws + OFF_SYNC, 0, OFF_TAB - OFF_SYNC, stream);
    gi_gemm<<<dim3(1024, 15), 256, 0, stream>>>(x, encWih, encBih, gi);
    table_k<<<456, 256, 0, stream>>>(emb, decWih, decBih, tab);
    tcal_k<<<32, 256, 0, stream>>>(target, out);
    rnn_persist<<<256, 1024, 0, stream>>>(gi, encWhh, encBhh, decWhh, decBhh, tab,
                                          linW, linB, target, hglob, syncA, abrt, out);
}

// Round 3
// 3358.824 us; speedup vs baseline: 4.5442x; 4.5442x over previous
//
#include <hip/hip_runtime.h>
#include <cstdint>
#include <cstddef>

// Problem constants
#define HN 304      // hidden size
#define G3 912      // 3*HN gate rows
#define US 76       // hidden units per slice (HN/4)
#define RS 228      // rows per slice (3*US)
#define NB 64       // batch
#define TSTEPS 1024 // encoder steps
#define LDEC 127    // decoder steps actually needed (L-1)
#define DCLS 128    // vocab / classes

// Output layout (floats): [softmax_cal 8128*128][target_cal 8128][asr_outputs 8128]
#define OUT_O1 1040384
#define OUT_O2 1048512

// Workspace layout (bytes). Proven available: ws_size >= 239,702,784 (R1/R2 ran).
static const size_t OFF_GI   = 0;             // 64*1024*912 f32 = 239,075,328
static const size_t OFF_HG   = 239075328ull;  // h ping-pong: 2*64*304 f32 = 155,648
static const size_t OFF_SF   = 239230976ull;  // h flags: 64*4 int = 1,024
static const size_t OFF_AM   = 239232000ull;  // argmax tagged: 64*4 ull = 2,048
static const size_t OFF_ABRT = 239234048ull;  // 256
static const size_t OFF_TAB  = 239234304ull;  // 128*912 f32 = 466,944
static const size_t WS_NEED  = 239701248ull;  // <= 239,702,784 proven bound

// ---------------------------------------------------------------------------
// Phase 1: gi[b,t,:] = x[b,t,:] @ enc_Wih^T + enc_bih   (M=65536, N=912, K=304)
// ---------------------------------------------------------------------------
__global__ __launch_bounds__(256) void gi_gemm(const float* __restrict__ X,
                                               const float* __restrict__ W,
                                               const float* __restrict__ bias,
                                               float* __restrict__ out)
{
    __shared__ float xs[16][68];
    __shared__ float wsm[16][68];
    const int tid = threadIdx.x;
    const int m0 = blockIdx.x * 64;
    const int n0 = blockIdx.y * 64;
    const int tx = tid & 15, ty = tid >> 4;
    const int lr = tid >> 2;
    const int lk = (tid & 3) * 4;
    float c[4][4];
#pragma unroll
    for (int i = 0; i < 4; ++i)
#pragma unroll
        for (int j = 0; j < 4; ++j) c[i][j] = 0.f;

    for (int k0 = 0; k0 < HN; k0 += 16) {
        float4 xv = *(const float4*)(X + (size_t)(m0 + lr) * HN + k0 + lk);
        float4 wv = make_float4(0.f, 0.f, 0.f, 0.f);
        if (n0 + lr < G3) wv = *(const float4*)(W + (size_t)(n0 + lr) * HN + k0 + lk);
        xs[lk + 0][lr] = xv.x; xs[lk + 1][lr] = xv.y; xs[lk + 2][lr] = xv.z; xs[lk + 3][lr] = xv.w;
        wsm[lk + 0][lr] = wv.x; wsm[lk + 1][lr] = wv.y; wsm[lk + 2][lr] = wv.z; wsm[lk + 3][lr] = wv.w;
        __syncthreads();
#pragma unroll
        for (int kk = 0; kk < 16; ++kk) {
            const float4 a4 = *(const float4*)&xs[kk][ty * 4];
            const float4 b4 = *(const float4*)&wsm[kk][tx * 4];
            c[0][0] += a4.x * b4.x; c[0][1] += a4.x * b4.y; c[0][2] += a4.x * b4.z; c[0][3] += a4.x * b4.w;
            c[1][0] += a4.y * b4.x; c[1][1] += a4.y * b4.y; c[1][2] += a4.y * b4.z; c[1][3] += a4.y * b4.w;
            c[2][0] += a4.z * b4.x; c[2][1] += a4.z * b4.y; c[2][2] += a4.z * b4.z; c[2][3] += a4.z * b4.w;
            c[3][0] += a4.w * b4.x; c[3][1] += a4.w * b4.y; c[3][2] += a4.w * b4.z; c[3][3] += a4.w * b4.w;
        }
        __syncthreads();
    }
#pragma unroll
    for (int i = 0; i < 4; ++i) {
        const int m = m0 + ty * 4 + i;
#pragma unroll
        for (int j = 0; j < 4; ++j) {
            const int n = n0 + tx * 4 + j;
            if (n < G3) out[(size_t)m * G3 + n] = c[i][j] + bias[n];
        }
    }
}

// ---------------------------------------------------------------------------
// Phase 1b: decoder input-projection table
// ---------------------------------------------------------------------------
__global__ __launch_bounds__(256) void table_k(const float* __restrict__ emb,
                                               const float* __restrict__ Wih,
                                               const float* __restrict__ bih,
                                               float* __restrict__ tab)
{
    const int idx = blockIdx.x * 256 + threadIdx.x;  // 456*256 = 116736 = 128*912
    const int d = idx / G3;
    const int R = idx - d * G3;
    const float4* e4 = (const float4*)(emb + (size_t)d * HN);
    const float4* w4 = (const float4*)(Wih + (size_t)R * HN);
    float acc = 0.f;
#pragma unroll
    for (int j = 0; j < 76; ++j) {
        const float4 e = e4[j], w = w4[j];
        acc += e.x * w.x; acc += e.y * w.y; acc += e.z * w.z; acc += e.w * w.w;
    }
    tab[idx] = acc + bih[R];
}

// target_cal output
__global__ void tcal_k(const int* __restrict__ target, float* __restrict__ out)
{
    const int i = blockIdx.x * 256 + threadIdx.x;
    if (i < NB * LDEC) {
        const int b = i / LDEC;
        const int t = i - b * LDEC;
        out[OUT_O1 + i] = (float)target[b * 128 + t + 1];
    }
}

// relaxed-only spin (NO acquire: agent-scope acquire emits buffer_inv = full
// L2 invalidate, which was the R1/R2 ~10us/step killer). Relaxed agent-scope
// atomics are sc0+sc1 (L1/L2 bypass, served at L3) -> no cache maintenance.
__device__ __forceinline__ void spin_ge(int* f, int tgt, int* abortf)
{
    int g = 0;
    while (__hip_atomic_load(f, __ATOMIC_RELAXED, __HIP_MEMORY_SCOPE_AGENT) < tgt) {
        if ((++g & 255) == 0) {
            if (__hip_atomic_load(abortf, __ATOMIC_RELAXED, __HIP_MEMORY_SCOPE_AGENT) != 0) return;
            if (g > (1 << 19)) {  // deadlock valve: fail loudly, don't hang
                __hip_atomic_store(abortf, 1, __ATOMIC_RELAXED, __HIP_MEMORY_SCOPE_AGENT);
                return;
            }
        }
    }
}

// tagged 8B poll: wait until tag field (high 32b, signed) >= want, return payload
__device__ __forceinline__ unsigned long long spin_tag(unsigned long long* p, int want, int* abortf)
{
    int g = 0;
    unsigned long long r;
    for (;;) {
        r = __hip_atomic_load(p, __ATOMIC_RELAXED, __HIP_MEMORY_SCOPE_AGENT);
        if ((int)(r >> 32) >= want) return r;
        if ((++g & 255) == 0) {
            if (__hip_atomic_load(abortf, __ATOMIC_RELAXED, __HIP_MEMORY_SCOPE_AGENT) != 0) return r;
            if (g > (1 << 19)) {
                __hip_atomic_store(abortf, 1, __ATOMIC_RELAXED, __HIP_MEMORY_SCOPE_AGENT);
                return r;
            }
        }
    }
}

// ---------------------------------------------------------------------------
// Phase 2: persistent recurrence. 256 WGs x 1024 threads, 1 WG/CU.
// WG w: batch b = w & 63, slice s = w >> 6.
// Sync protocol (all relaxed agent atomics, zero cache-maintenance ops):
//   producer: h stores (relaxed, ->L3) ; __syncthreads (vmcnt(0) drain) ;
//             tid0 relaxed flag store.
//   consumer: relaxed spin on flag ; s_waitcnt(0) (ordering only) ; relaxed h load.
// h flags: encoder step t -> t+1 (1..1024); decoder step t -> 1025+t. Parity
// double-buffer on flag&1 (overwrite-safe by induction: publishing f+2 requires
// having consumed f+1 from all partners).
// Decoder argmax: single 8B tagged slot per (b,s): high32 = ((t+1)<<8)|idx,
// low32 = float bits. Single-buffered (the intra-step h exchange paces it).
// ---------------------------------------------------------------------------
__global__ __launch_bounds__(1024) void rnn_persist(
    const float* __restrict__ gi,
    const float* __restrict__ encWhh, const float* __restrict__ encBhh,
    const float* __restrict__ decWhh, const float* __restrict__ decBhh,
    const float* __restrict__ tab,
    const float* __restrict__ linW, const float* __restrict__ linB,
    const int* __restrict__ target,
    float* hglob, int* syncF, unsigned long long* amax, int* abortf, float* out)
{
    const int w = blockIdx.x;
    const int b = w & 63;
    const int s = w >> 6;
    const int tid = threadIdx.x;

    __shared__ alignas(16) float hbuf[HN];
    __shared__ alignas(16) float part[4][RS];
    __shared__ alignas(16) float lpart[32][9];
    __shared__ float logit_s[32];
    __shared__ float amx_v[4];
    __shared__ int   amx_i[4];

    const int ks = tid / RS;           // k-slice 0..3 (tid>=912 idle in GEMV)
    const int lr = tid - ks * RS;      // local row 0..227
    const bool comp = (tid < 912);
    const int g = lr / US;             // gate 0=r,1=z,2=n
    const int ul = lr - g * US;        // unit within slice
    const int Rrow = g * HN + s * US + ul;
    const int u = s * US + tid;        // global hidden unit for tid<76
    const int cq = tid / US;           // slice owning unit `tid` (tid<304)

    int* flags = syncF + b * 4;        // 4 h-flags for this batch
    unsigned long long* amx = amax + b * 4;

    // ---- encoder Whh slice into registers (76 f32 per thread)
    float4 wreg[19];
    if (comp) {
        const float4* wp = (const float4*)(encWhh + (size_t)Rrow * HN + (size_t)ks * US);
#pragma unroll
        for (int j = 0; j < 19; ++j) wreg[j] = wp[j];
    }
    float b_r = 0.f, b_z = 0.f, b_n = 0.f;
    if (tid < US) { b_r = encBhh[u]; b_z = encBhh[HN + u]; b_n = encBhh[2 * HN + u]; }

    for (int i = tid; i < HN; i += 1024) hbuf[i] = 0.f;   // h0 = 0
    __syncthreads();

    const float* gib = gi + (size_t)b * TSTEPS * G3;

    // ================= encoder: 1024 steps =================
    for (int t = 0; t < TSTEPS; ++t) {
        const int flagv = t + 1;
        const int buf = flagv & 1;
        float gr = 0.f, gz = 0.f, gn = 0.f;
        if (tid < US) {                       // gi prefetch, hidden behind GEMV
            const float* gp = gib + (size_t)t * G3;
            gr = gp[u]; gz = gp[HN + u]; gn = gp[2 * HN + u];
        }
        if (comp) {
            const float4* hp = (const float4*)(hbuf + ks * US);
            float acc = 0.f;
#pragma unroll
            for (int j = 0; j < 19; ++j) {
                const float4 h4 = hp[j], w4 = wreg[j];
                acc += w4.x * h4.x; acc += w4.y * h4.y; acc += w4.z * h4.z; acc += w4.w * h4.w;
            }
            part[ks][lr] = acc;
        }
        __syncthreads();
        if (tid < US) {
            const float ghr = part[0][tid] + part[1][tid] + part[2][tid] + part[3][tid] + b_r;
            const float ghz = part[0][US + tid] + part[1][US + tid] + part[2][US + tid] + part[3][US + tid] + b_z;
            const float ghn = part[0][2 * US + tid] + part[1][2 * US + tid] + part[2][2 * US + tid] + part[3][2 * US + tid] + b_n;
            const float r = 1.f / (1.f + expf(-(gr + ghr)));
            const float z = 1.f / (1.f + expf(-(gz + ghz)));
            const float n = tanhf(gn + r * ghn);
            const float hnew = (1.f - z) * n + z * hbuf[u];
            hbuf[u] = hnew;                   // own slice direct to LDS
            __hip_atomic_store(&hglob[buf * NB * HN + b * HN + u], hnew,
                               __ATOMIC_RELAXED, __HIP_MEMORY_SCOPE_AGENT);
        }
        __syncthreads();                      // per-wave s_waitcnt vmcnt(0): h is in L3
        if (tid == 0)
            __hip_atomic_store(&flags[s], flagv, __ATOMIC_RELAXED, __HIP_MEMORY_SCOPE_AGENT);
        if (tid < HN && cq != s) {            // fetch remote slices
            spin_ge(&flags[cq], flagv, abortf);
            __builtin_amdgcn_s_waitcnt(0);    // order h load after poll (no cache ops)
            hbuf[tid] = __hip_atomic_load(&hglob[buf * NB * HN + b * HN + tid],
                                          __ATOMIC_RELAXED, __HIP_MEMORY_SCOPE_AGENT);
        }
        __syncthreads();
    }

    // ================= decoder: 127 steps =================
    if (comp) {
        const float4* wp = (const float4*)(decWhh + (size_t)Rrow * HN + (size_t)ks * US);
#pragma unroll
        for (int j = 0; j < 19; ++j) wreg[j] = wp[j];
    }
    if (tid < US) { b_r = decBhh[u]; b_z = decBhh[HN + u]; b_n = decBhh[2 * HN + u]; }

    int tok = target[b * 128];         // target[b,0,0]
    const int lrow = tid >> 3;         // logit row within slice (tid<256)
    const int lks = tid & 7;           // 8 k-slices of 38

    for (int t = 0; t < LDEC; ++t) {
        const int hflagv = 1025 + t;
        const int buf = hflagv & 1;
        float gr = 0.f, gz = 0.f, gn = 0.f;
        if (tid < US) {
            const float* tp = tab + (size_t)tok * G3;
            gr = tp[u]; gz = tp[HN + u]; gn = tp[2 * HN + u];
        }
        if (comp) {
            const float4* hp = (const float4*)(hbuf + ks * US);
            float acc = 0.f;
#pragma unroll
            for (int j = 0; j < 19; ++j) {
                const float4 h4 = hp[j], w4 = wreg[j];
                acc += w4.x * h4.x; acc += w4.y * h4.y; acc += w4.z * h4.z; acc += w4.w * h4.w;
            }
            part[ks][lr] = acc;
        }
        __syncthreads();
        if (tid < US) {
            const float ghr = part[0][tid] + part[1][tid] + part[2][tid] + part[3][tid] + b_r;
            const float ghz = part[0][US + tid] + part[1][US + tid] + part[2][US + tid] + part[3][US + tid] + b_z;
            const float ghn = part[0][2 * US + tid] + part[1][2 * US + tid] + part[2][2 * US + tid] + part[3][2 * US + tid] + b_n;
            const float r = 1.f / (1.f + expf(-(gr + ghr)));
            const float z = 1.f / (1.f + expf(-(gz + ghz)));
            const float n = tanhf(gn + r * ghn);
            const float hnew = (1.f - z) * n + z * hbuf[u];
            hbuf[u] = hnew;
            __hip_atomic_store(&hglob[buf * NB * HN + b * HN + u], hnew,
                               __ATOMIC_RELAXED, __HIP_MEMORY_SCOPE_AGENT);
        }
        __syncthreads();
        if (tid == 0)
            __hip_atomic_store(&flags[s], hflagv, __ATOMIC_RELAXED, __HIP_MEMORY_SCOPE_AGENT);
        if (tid < HN && cq != s) {
            spin_ge(&flags[cq], hflagv, abortf);
            __builtin_amdgcn_s_waitcnt(0);
            hbuf[tid] = __hip_atomic_load(&hglob[buf * NB * HN + b * HN + tid],
                                          __ATOMIC_RELAXED, __HIP_MEMORY_SCOPE_AGENT);
        }
        __syncthreads();                      // hbuf fresh for logits

        // logits rows [32s, 32s+32)
        if (tid < 256) {
            const float2* wl = (const float2*)(linW + (size_t)(s * 32 + lrow) * HN + (size_t)lks * 38);
            const float2* hl = (const float2*)(hbuf + lks * 38);
            float a = 0.f;
#pragma unroll
            for (int j = 0; j < 19; ++j) { const float2 wv = wl[j], hv = hl[j]; a += wv.x * hv.x; a += wv.y * hv.y; }
            lpart[lrow][lks] = a;
        }
        __syncthreads();
        if (tid < 32) {
            const float lg = lpart[tid][0] + lpart[tid][1] + lpart[tid][2] + lpart[tid][3]
                           + lpart[tid][4] + lpart[tid][5] + lpart[tid][6] + lpart[tid][7]
                           + linB[s * 32 + tid];
            logit_s[tid] = lg;
            out[((size_t)b * LDEC + t) * DCLS + s * 32 + tid] = lg;   // softmax_cal
        }
        __syncthreads();
        if (tid == 0) {                       // publish local argmax: one tagged 8B store
            float bv = logit_s[0]; int bi = 0;
            for (int i = 1; i < 32; ++i) { const float v = logit_s[i]; if (v > bv) { bv = v; bi = i; } }
            const unsigned tagf = (unsigned)(((t + 1) << 8) | (s * 32 + bi));
            const unsigned long long pk = ((unsigned long long)tagf << 32) | (unsigned long long)__float_as_uint(bv);
            __hip_atomic_store(&amx[s], pk, __ATOMIC_RELAXED, __HIP_MEMORY_SCOPE_AGENT);
        }
        if (tid < 4) {                        // poll all 4 slices' argmaxes in parallel
            const unsigned long long r = spin_tag(&amx[tid], (t + 1) << 8, abortf);
            amx_v[tid] = __uint_as_float((unsigned)r);
            amx_i[tid] = (int)(r >> 32) & 255;
        }
        __syncthreads();
        {                                     // all threads compute identical winner
            float gbv = amx_v[0]; int gbi = amx_i[0];
            if (amx_v[1] > gbv) { gbv = amx_v[1]; gbi = amx_i[1]; }
            if (amx_v[2] > gbv) { gbv = amx_v[2]; gbi = amx_i[2]; }
            if (amx_v[3] > gbv) { gbv = amx_v[3]; gbi = amx_i[3]; }
            tok = gbi;
            if (tid == 0 && s == 0) out[OUT_O2 + (size_t)b * LDEC + t] = (float)gbi;  // asr_outputs
        }
    }
}

// ---------------------------------------------------------------------------
extern "C" void kernel_launch(void* const* d_in, const int* in_sizes, int n_in,
                              void* d_out, int out_size, void* d_ws, size_t ws_size,
                              hipStream_t stream)
{
    (void)in_sizes; (void)n_in; (void)out_size;
    const float* x      = (const float*)d_in[0];
    const int*   target = (const int*)  d_in[1];
    const float* emb    = (const float*)d_in[2];
    const float* encWih = (const float*)d_in[3];
    const float* encWhh = (const float*)d_in[4];
    const float* encBih = (const float*)d_in[5];
    const float* encBhh = (const float*)d_in[6];
    const float* decWih = (const float*)d_in[7];
    const float* decWhh = (const float*)d_in[8];
    const float* decBih = (const float*)d_in[9];
    const float* decBhh = (const float*)d_in[10];
    const float* linW   = (const float*)d_in[11];
    const float* linB   = (const float*)d_in[12];
    float* out = (float*)d_out;
    char* ws = (char*)d_ws;

    if (ws_size < WS_NEED) return;  // insufficient scratch: fail visibly

    float*              gi    = (float*)(ws + OFF_GI);
    float*              hglob = (float*)(ws + OFF_HG);
    int*                syncF = (int*)  (ws + OFF_SF);
    unsigned long long* amax  = (unsigned long long*)(ws + OFF_AM);
    int*                abrt  = (int*)  (ws + OFF_ABRT);
    float*              tab   = (float*)(ws + OFF_TAB);

    // Only the abort flag must be zero. h-flags / amax tags rely on 0xAA poison
    // reading as negative (spin predicates are signed >=).
    hipMemsetAsync(ws + OFF_ABRT, 0, 256, stream);
    gi_gemm<<<dim3(1024, 15), 256, 0, stream>>>(x, encWih, encBih, gi);
    table_k<<<456, 256, 0, stream>>>(emb, decWih, decBih, tab);
    tcal_k<<<32, 256, 0, stream>>>(target, out);
    rnn_persist<<<256, 1024, 0, stream>>>(gi, encWhh, encBhh, decWhh, decBhh, tab,
                                          linW, linB, target, hglob, syncF, amax,
                                          abrt, out);
}